// Round 3
// baseline (543.100 us; speedup 1.0000x reference)
//
#include <hip/hip_runtime.h>
#include <stdint.h>

typedef __attribute__((ext_vector_type(8))) short short8;
typedef __attribute__((ext_vector_type(4))) float float4v;

#define SEQ 4096
#define HD 64
#define QB 64
#define KT 64
#define HEADS 16
#define MWORDS (SEQ / 64)       // uint64 mask words per row
#define TILE_BYTES 8192         // 64x64 bf16, fragment-order layout

__device__ __forceinline__ ushort f2bf(float f) {
    union { float f; uint32_t u; } x; x.f = f;
    uint32_t u = x.u;
    return (ushort)((u + 0x7FFFu + ((u >> 16) & 1u)) >> 16);  // RNE
}

__device__ __forceinline__ uint32_t cvt_pk_bf16(float lo, float hi) {
    uint32_t r;
    asm("v_cvt_pk_bf16_f32 %0, %1, %2" : "=v"(r) : "v"(lo), "v"(hi));
    return r;
}

// ---------------- mask bit-pack: [4096][4096] int32 -> [4096][64] uint64 ----------------
__global__ __launch_bounds__(256) void pack_mask_kernel(const int* __restrict__ mask,
                                                        unsigned long long* __restrict__ mb) {
    const int qrow = blockIdx.x;
    const int wave = threadIdx.x >> 6;
    const int lane = threadIdx.x & 63;
    const int* rp = mask + (size_t)qrow * SEQ;
    #pragma unroll
    for (int i = 0; i < 16; ++i) {
        const int widx = wave * 16 + i;
        const int mv = rp[widx * 64 + lane];
        unsigned long long b = __ballot(mv != 0);
        if (lane == 0) mb[(size_t)qrow * MWORDS + widx] = b;
    }
}

// ---------------- K/V -> bf16 tiles in MFMA fragment order ----------------
// chunk c = (t*2+h)*64 + lane  (lane = g*16+li), 16B per chunk:
//   K tile:  K[t*16+li][h*32+g*8 + e]      (B-operand for QK^T)
//   V tile:  V[h*32+g*8+e][dt*16+li]       (B-operand for PV, i.e. V^T rows=d)
__global__ __launch_bounds__(256) void prep_kv_kernel(const float* __restrict__ kg,
                                                      const float* __restrict__ vg,
                                                      char* __restrict__ ktiles,
                                                      char* __restrict__ vtiles) {
    __shared__ __align__(16) float Tl[64][68];
    const int bid = blockIdx.x;               // head*64 + kt
    const int tid = threadIdx.x;
    const float* Kg = kg + (size_t)bid * KT * HD;
    const float* Vg = vg + (size_t)bid * KT * HD;
    char* Kt = ktiles + (size_t)bid * TILE_BYTES;
    char* Vt = vtiles + (size_t)bid * TILE_BYTES;

    {   // stage K coalesced
        const int r = tid >> 2, c0 = (tid & 3) * 16;
        #pragma unroll
        for (int j = 0; j < 4; ++j)
            *(float4v*)&Tl[r][c0 + j * 4] = *(const float4v*)(Kg + r * HD + c0 + j * 4);
    }
    __syncthreads();
    #pragma unroll
    for (int cc = 0; cc < 2; ++cc) {
        const int c = tid + cc * 256;
        const int t = c >> 7, h = (c >> 6) & 1, g = (c >> 4) & 3, li = c & 15;
        const float* src = &Tl[t * 16 + li][h * 32 + g * 8];
        short8 w;
        #pragma unroll
        for (int e = 0; e < 8; ++e) w[e] = (short)f2bf(src[e]);
        *(short8*)(Kt + c * 16) = w;
    }
    __syncthreads();
    {   // stage V coalesced
        const int r = tid >> 2, c0 = (tid & 3) * 16;
        #pragma unroll
        for (int j = 0; j < 4; ++j)
            *(float4v*)&Tl[r][c0 + j * 4] = *(const float4v*)(Vg + r * HD + c0 + j * 4);
    }
    __syncthreads();
    #pragma unroll
    for (int cc = 0; cc < 2; ++cc) {
        const int c = tid + cc * 256;
        const int dt = c >> 7, h = (c >> 6) & 1, g = (c >> 4) & 3, li = c & 15;
        short8 w;
        #pragma unroll
        for (int e = 0; e < 8; ++e) w[e] = (short)f2bf(Tl[h * 32 + g * 8 + e][dt * 16 + li]);
        *(short8*)(Vt + c * 16) = w;
    }
}

// ---------------- fused attention: barrier-free, per block = one (head, 64-row q-block) --
__global__ __launch_bounds__(256, 3) void attn_kernel(
    const float* __restrict__ qg, const unsigned long long* __restrict__ mb,
    const char* __restrict__ ktiles, const char* __restrict__ vtiles,
    float* __restrict__ outg, float* __restrict__ attng)
{
    __shared__ __align__(16) float Pf[4][16 * 64];   // per-wave f32 P tile, XOR-swizzled

    const int tid  = threadIdx.x;
    const int wave = tid >> 6;
    const int lane = tid & 63;
    const int g    = lane >> 4;
    const int li   = lane & 15;

    // XCD-aware swizzle: 2 heads (128 blocks) per XCD -> K/V tiles L2-resident
    const int bid = blockIdx.x;
    const int blk = (bid & 7) * 128 + (bid >> 3);
    const int bh  = blk >> 6;
    const int qb  = blk & 63;

    const size_t qkvBase = (size_t)bh * SEQ * HD;
    const float* Qg = qg + qkvBase + (size_t)qb * QB * HD;
    const char* Ktile = ktiles + (size_t)bh * (SEQ / KT) * TILE_BYTES;
    const char* Vtile = vtiles + (size_t)bh * (SEQ / KT) * TILE_BYTES;

    // ---- Q A-fragments (scale 1/8 folded) ----
    const int wq0 = wave * 16;
    short8 aq[2];
    #pragma unroll
    for (int h = 0; h < 2; ++h) {
        const float* src = Qg + (wq0 + li) * HD + h * 32 + g * 8;
        short8 t;
        #pragma unroll
        for (int e = 0; e < 8; ++e) t[e] = (short)f2bf(src[e] * 0.125f);
        aq[h] = t;
    }

    const int qrow0 = qb * QB + wq0 + g * 4;
    const unsigned long long* mrow[4];
    #pragma unroll
    for (int r = 0; r < 4; ++r) mrow[r] = mb + (size_t)(qrow0 + r) * MWORDS;

    // ================= pass 1: row sums (no LDS, no barriers) =================
    float lsum[4] = {0.f, 0.f, 0.f, 0.f};
    for (int kt = 0; kt < SEQ / KT; ++kt) {
        const char* Kb = Ktile + kt * TILE_BYTES + lane * 16;
        short8 bk[4][2];
        #pragma unroll
        for (int t = 0; t < 4; ++t)
            #pragma unroll
            for (int h = 0; h < 2; ++h)
                bk[t][h] = *(const short8*)(Kb + (t * 2 + h) * 1024);
        unsigned long long mw[4];
        #pragma unroll
        for (int r = 0; r < 4; ++r) mw[r] = mrow[r][kt];

        float4v accs[4];
        #pragma unroll
        for (int t = 0; t < 4; ++t) accs[t] = (float4v){0.f, 0.f, 0.f, 0.f};
        #pragma unroll
        for (int t = 0; t < 4; ++t) {
            accs[t] = __builtin_amdgcn_mfma_f32_16x16x32_bf16(aq[0], bk[t][0], accs[t], 0, 0, 0);
            accs[t] = __builtin_amdgcn_mfma_f32_16x16x32_bf16(aq[1], bk[t][1], accs[t], 0, 0, 0);
        }
        #pragma unroll
        for (int t = 0; t < 4; ++t) {
            #pragma unroll
            for (int r = 0; r < 4; ++r) {
                const int bit = t * 16 + li;
                lsum[r] += ((mw[r] >> bit) & 1ull) ? __expf(accs[t][r]) : 0.f;
            }
        }
    }

    float invl[4];
    #pragma unroll
    for (int r = 0; r < 4; ++r) {
        float s = lsum[r];
        s += __shfl_xor(s, 1); s += __shfl_xor(s, 2);
        s += __shfl_xor(s, 4); s += __shfl_xor(s, 8);
        invl[r] = 1.f / s;
    }

    // ================= pass 2: write attn, accumulate out =================
    float* attnW = attng + (size_t)bh * SEQ * SEQ;
    char* Pfw = (char*)&Pf[wave][0];
    float4v acco[4];
    #pragma unroll
    for (int dt = 0; dt < 4; ++dt) acco[dt] = (float4v){0.f, 0.f, 0.f, 0.f};

    for (int kt = 0; kt < SEQ / KT; ++kt) {
        const char* Kb = Ktile + kt * TILE_BYTES + lane * 16;
        const char* Vb = Vtile + kt * TILE_BYTES + lane * 16;
        short8 bk[4][2], vb[4][2];
        #pragma unroll
        for (int t = 0; t < 4; ++t)
            #pragma unroll
            for (int h = 0; h < 2; ++h) {
                bk[t][h] = *(const short8*)(Kb + (t * 2 + h) * 1024);
                vb[t][h] = *(const short8*)(Vb + (t * 2 + h) * 1024);
            }
        unsigned long long mw[4];
        #pragma unroll
        for (int r = 0; r < 4; ++r) mw[r] = mrow[r][kt];

        float4v accs[4];
        #pragma unroll
        for (int t = 0; t < 4; ++t) accs[t] = (float4v){0.f, 0.f, 0.f, 0.f};
        #pragma unroll
        for (int t = 0; t < 4; ++t) {
            accs[t] = __builtin_amdgcn_mfma_f32_16x16x32_bf16(aq[0], bk[t][0], accs[t], 0, 0, 0);
            accs[t] = __builtin_amdgcn_mfma_f32_16x16x32_bf16(aq[1], bk[t][1], accs[t], 0, 0, 0);
        }

        // p -> per-wave f32 LDS tile (row = g*4+r, col = t*16+li), XOR-swizzled
        #pragma unroll
        for (int t = 0; t < 4; ++t) {
            #pragma unroll
            for (int r = 0; r < 4; ++r) {
                const int bit = t * 16 + li;
                const float p = ((mw[r] >> bit) & 1ull) ? __expf(accs[t][r]) * invl[r] : 0.f;
                const int row = g * 4 + r;
                const uint32_t off = (uint32_t)(row * 256 + (t * 16 + li) * 4) ^ ((uint32_t)(row & 7) << 4);
                *(float*)(Pfw + off) = p;
            }
        }

        // PV A-fragment: rows = li, cols h*32+g*8..+7, f32 -> bf16 via cvt_pk
        short8 pa[2];
        #pragma unroll
        for (int h = 0; h < 2; ++h) {
            const uint32_t b0 = (uint32_t)(li * 256 + h * 128 + g * 32);
            const uint32_t swz = (uint32_t)(li & 7) << 4;
            const float4v plo = *(const float4v*)(Pfw + (b0 ^ swz));
            const float4v phi = *(const float4v*)(Pfw + ((b0 + 16) ^ swz));
            union { uint32_t u[4]; short8 s8; } pk;
            pk.u[0] = cvt_pk_bf16(plo[0], plo[1]);
            pk.u[1] = cvt_pk_bf16(plo[2], plo[3]);
            pk.u[2] = cvt_pk_bf16(phi[0], phi[1]);
            pk.u[3] = cvt_pk_bf16(phi[2], phi[3]);
            pa[h] = pk.s8;
        }

        // attn store: float4 per lane, 128B contiguous per 8 lanes
        #pragma unroll
        for (int half = 0; half < 2; ++half) {
            const int row = half * 8 + (lane >> 3);
            #pragma unroll
            for (int i = 0; i < 2; ++i) {
                const int chunk = (lane & 7) + 8 * i;
                const float4v w = *(const float4v*)(Pfw + (((uint32_t)(row * 256 + chunk * 16)) ^ ((uint32_t)(row & 7) << 4)));
                *(float4v*)(attnW + (size_t)(qb * QB + wq0 + row) * SEQ + kt * KT + chunk * 4) = w;
            }
        }

        // PV: out[16q][64d] += P * V
        #pragma unroll
        for (int dt = 0; dt < 4; ++dt) {
            acco[dt] = __builtin_amdgcn_mfma_f32_16x16x32_bf16(pa[0], vb[dt][0], acco[dt], 0, 0, 0);
            acco[dt] = __builtin_amdgcn_mfma_f32_16x16x32_bf16(pa[1], vb[dt][1], acco[dt], 0, 0, 0);
        }
    }

    // ---- write output ----
    float* outW = outg + qkvBase + (size_t)qb * QB * HD;
    #pragma unroll
    for (int dt = 0; dt < 4; ++dt) {
        #pragma unroll
        for (int r = 0; r < 4; ++r) {
            outW[(wq0 + g * 4 + r) * HD + dt * 16 + li] = acco[dt][r];
        }
    }
}

extern "C" void kernel_launch(void* const* d_in, const int* in_sizes, int n_in,
                              void* d_out, int out_size, void* d_ws, size_t ws_size,
                              hipStream_t stream) {
    (void)in_sizes; (void)n_in; (void)out_size; (void)ws_size;
    const float* q = (const float*)d_in[0];
    const float* k = (const float*)d_in[1];
    const float* v = (const float*)d_in[2];
    const int* mask = (const int*)d_in[3];

    float* outp  = (float*)d_out;
    float* attnp = outp + (size_t)2 * 8 * SEQ * HD;

    // ws layout: [0,2MB) mask bits | [2MB,10MB) K tiles | [10MB,18MB) V tiles
    char* ws = (char*)d_ws;
    unsigned long long* mb = (unsigned long long*)ws;
    char* ktiles = ws + (size_t)2 * 1024 * 1024;
    char* vtiles = ws + (size_t)10 * 1024 * 1024;

    pack_mask_kernel<<<SEQ, 256, 0, stream>>>(mask, mb);
    prep_kv_kernel<<<HEADS * (SEQ / KT), 256, 0, stream>>>(k, v, ktiles, vtiles);
    attn_kernel<<<HEADS * (SEQ / QB), 256, 0, stream>>>(q, mb, ktiles, vtiles, outp, attnp);
}

// Round 6
// 445.670 us; speedup vs baseline: 1.2186x; 1.2186x over previous
//
#include <hip/hip_runtime.h>
#include <stdint.h>

typedef __attribute__((ext_vector_type(8))) short short8;
typedef __attribute__((ext_vector_type(4))) float float4v;

#define SEQ 4096
#define HD 64
#define QB 64
#define KT 64
#define HEADS 16
#define MWORDS (SEQ / 64)       // uint64 mask words per row
#define TILE_BYTES 8192         // 64x64 bf16, fragment-order layout
#define QSCALE 0.18033688f      // 0.125 * log2(e)  (temperature + exp2 folding)

__device__ __forceinline__ ushort f2bf(float f) {
    union { float f; uint32_t u; } x; x.f = f;
    uint32_t u = x.u;
    return (ushort)((u + 0x7FFFu + ((u >> 16) & 1u)) >> 16);  // RNE
}

__device__ __forceinline__ uint32_t cvt_pk_bf16(float lo, float hi) {
    uint32_t r;
    asm("v_cvt_pk_bf16_f32 %0, %1, %2" : "=v"(r) : "v"(lo), "v"(hi));
    return r;
}

__device__ __forceinline__ float exp2_hw(float x) { return __builtin_amdgcn_exp2f(x); }
__device__ __forceinline__ float log2_hw(float x) { return __builtin_amdgcn_logf(x); }

__device__ __forceinline__ void gload_lds16(const void* g, void* l) {
    __builtin_amdgcn_global_load_lds(
        (const __attribute__((address_space(1))) uint32_t*)g,
        (__attribute__((address_space(3))) uint32_t*)l, 16, 0, 0);
}

// ---------------- mask bit-pack: [4096][4096] int32 -> [4096][64] uint64 ----------------
__global__ __launch_bounds__(256) void pack_mask_kernel(const int* __restrict__ mask,
                                                        unsigned long long* __restrict__ mb) {
    const int qrow = blockIdx.x;
    const int wave = threadIdx.x >> 6;
    const int lane = threadIdx.x & 63;
    const int* rp = mask + (size_t)qrow * SEQ;
    #pragma unroll
    for (int i = 0; i < 16; ++i) {
        const int widx = wave * 16 + i;
        const int mv = rp[widx * 64 + lane];
        unsigned long long b = __ballot(mv != 0);
        if (lane == 0) mb[(size_t)qrow * MWORDS + widx] = b;
    }
}

// ---------------- K/V -> bf16 tiles in MFMA fragment order ----------------
// K tile chunk ci = t*2+h, lane = g*16+li, 16B per lane:
//   K[kv(t,li)][h*32+g*8+e],  kv(t,m) = 32*(t>>1) + 8*(m>>2) + 4*(t&1) + (m&3)
//   (custom kv permutation makes PV's B-fragment a register rename of QK^T output)
// V tile chunk ci = dt*2+h:  V[h*32+g*8+e][dt*16+li]   (V^T fragment)
__global__ __launch_bounds__(256) void prep_kv_kernel(const float* __restrict__ kg,
                                                      const float* __restrict__ vg,
                                                      char* __restrict__ ktiles,
                                                      char* __restrict__ vtiles) {
    __shared__ __align__(16) float Tl[64][68];
    const int bid = blockIdx.x;               // head*64 + kt
    const int tid = threadIdx.x;
    const float* Kg = kg + (size_t)bid * KT * HD;
    const float* Vg = vg + (size_t)bid * KT * HD;
    char* Kt = ktiles + (size_t)bid * TILE_BYTES;
    char* Vt = vtiles + (size_t)bid * TILE_BYTES;

    {   // stage K coalesced
        const int r = tid >> 2, c0 = (tid & 3) * 16;
        #pragma unroll
        for (int j = 0; j < 4; ++j)
            *(float4v*)&Tl[r][c0 + j * 4] = *(const float4v*)(Kg + r * HD + c0 + j * 4);
    }
    __syncthreads();
    #pragma unroll
    for (int cc = 0; cc < 2; ++cc) {
        const int c = tid + cc * 256;
        const int t = c >> 7, h = (c >> 6) & 1, g = (c >> 4) & 3, li = c & 15;
        const int row = 32 * (t >> 1) + 8 * (li >> 2) + 4 * (t & 1) + (li & 3);
        const float* src = &Tl[row][h * 32 + g * 8];
        short8 w;
        #pragma unroll
        for (int e = 0; e < 8; ++e) w[e] = (short)f2bf(src[e]);
        *(short8*)(Kt + c * 16) = w;
    }
    __syncthreads();
    {   // stage V coalesced
        const int r = tid >> 2, c0 = (tid & 3) * 16;
        #pragma unroll
        for (int j = 0; j < 4; ++j)
            *(float4v*)&Tl[r][c0 + j * 4] = *(const float4v*)(Vg + r * HD + c0 + j * 4);
    }
    __syncthreads();
    #pragma unroll
    for (int cc = 0; cc < 2; ++cc) {
        const int c = tid + cc * 256;
        const int dt = c >> 7, h = (c >> 6) & 1, g = (c >> 4) & 3, li = c & 15;
        short8 w;
        #pragma unroll
        for (int e = 0; e < 8; ++e) w[e] = (short)f2bf(Tl[h * 32 + g * 8 + e][dt * 16 + li]);
        *(short8*)(Vt + c * 16) = w;
    }
}

#define STAGE_K(KTI, DST) do {                                                     \
    const char* _s = Ktile + (size_t)(KTI) * TILE_BYTES + wave * 2048 + lane * 16; \
    char* _d = (char*)(DST) + wave * 2048;                                         \
    gload_lds16(_s, _d); gload_lds16(_s + 1024, _d + 1024);                        \
} while (0)

#define STAGE_V(KTI, DST) do {                                                     \
    const char* _s = Vtile + (size_t)(KTI) * TILE_BYTES + wave * 2048 + lane * 16; \
    char* _d = (char*)(DST) + wave * 2048;                                         \
    gload_lds16(_s, _d); gload_lds16(_s + 1024, _d + 1024);                        \
} while (0)

// ---------------- fused attention: swapped-MFMA, P fully in registers ----------------
__global__ __launch_bounds__(256, 4) void attn_kernel(
    const float* __restrict__ qg, const unsigned long long* __restrict__ mb,
    const char* __restrict__ ktiles, const char* __restrict__ vtiles,
    float* __restrict__ outg, float* __restrict__ attng)
{
    __shared__ __align__(16) char Ks[2][TILE_BYTES];
    __shared__ __align__(16) char Vs[2][TILE_BYTES];

    const int tid  = threadIdx.x;
    const int wave = tid >> 6;
    const int lane = tid & 63;
    const int g    = lane >> 4;
    const int li   = lane & 15;

    // XCD-aware swizzle: 2 heads (128 blocks) per XCD -> K/V tiles L2-resident
    const int bid = blockIdx.x;
    const int blk = (bid & 7) * 128 + (bid >> 3);
    const int bh  = blk >> 6;
    const int qb  = blk & 63;

    const size_t qkvBase = (size_t)bh * SEQ * HD;
    const float* Qg = qg + qkvBase + (size_t)qb * QB * HD;
    const char* Ktile = ktiles + (size_t)bh * (SEQ / KT) * TILE_BYTES;
    const char* Vtile = vtiles + (size_t)bh * (SEQ / KT) * TILE_BYTES;

    // ---- Q B-fragments (0.125 * log2e folded) ----
    const int wq0 = wave * 16;
    short8 aq[2];
    #pragma unroll
    for (int h = 0; h < 2; ++h) {
        const float* src = Qg + (wq0 + li) * HD + h * 32 + g * 8;
        short8 t;
        #pragma unroll
        for (int e = 0; e < 8; ++e) t[e] = (short)f2bf(src[e] * QSCALE);
        aq[h] = t;
    }

    const int qrow = qb * QB + wq0 + li;          // this lane's q row (within head)
    const unsigned long long* mrow = mb + (size_t)qrow * MWORDS;

    // ================= pass 1: row sums =================
    STAGE_K(0, Ks[0]);
    __syncthreads();
    int cur = 0;
    float lsum = 0.f;
    for (int kt = 0; kt < SEQ / KT; ++kt) {
        if (kt < SEQ / KT - 1) STAGE_K(kt + 1, Ks[cur ^ 1]);
        const unsigned long long mw = mrow[kt];
        const uint32_t mlo = (uint32_t)mw >> (g * 8);
        const uint32_t mhi = (uint32_t)(mw >> 32) >> (g * 8);

        const char* Kb = Ks[cur] + lane * 16;
        short8 bk[4][2];
        #pragma unroll
        for (int t = 0; t < 4; ++t)
            #pragma unroll
            for (int h = 0; h < 2; ++h)
                bk[t][h] = *(const short8*)(Kb + (t * 2 + h) * 1024);

        float4v accs[4];
        #pragma unroll
        for (int t = 0; t < 4; ++t) accs[t] = (float4v){0.f, 0.f, 0.f, 0.f};
        #pragma unroll
        for (int t = 0; t < 4; ++t) {
            accs[t] = __builtin_amdgcn_mfma_f32_16x16x32_bf16(bk[t][0], aq[0], accs[t], 0, 0, 0);
            accs[t] = __builtin_amdgcn_mfma_f32_16x16x32_bf16(bk[t][1], aq[1], accs[t], 0, 0, 0);
        }
        const uint32_t nib[4] = { mlo & 0xFu, (mlo >> 4) & 0xFu, mhi & 0xFu, (mhi >> 4) & 0xFu };
        #pragma unroll
        for (int t = 0; t < 4; ++t) {
            #pragma unroll
            for (int r = 0; r < 4; ++r) {
                const float e = exp2_hw(accs[t][r]);
                lsum += ((nib[t] >> r) & 1u) ? e : 0.f;
            }
        }
        __syncthreads();
        cur ^= 1;
    }
    // reduce across the 4 lanes sharing this li (g = 0..3)
    lsum += __shfl_xor(lsum, 16);
    lsum += __shfl_xor(lsum, 32);
    const float linv2 = -log2_hw(lsum);   // log2(1/l)

    // ================= pass 2: write attn, accumulate out =================
    float* attnT = attng + (size_t)bh * SEQ * SEQ + (size_t)qrow * SEQ + g * 8;
    float4v acco[4];
    #pragma unroll
    for (int dt = 0; dt < 4; ++dt) acco[dt] = (float4v){0.f, 0.f, 0.f, 0.f};

    STAGE_K(0, Ks[0]);
    STAGE_V(0, Vs[0]);
    __syncthreads();
    cur = 0;
    for (int kt = 0; kt < SEQ / KT; ++kt) {
        if (kt < SEQ / KT - 1) { STAGE_K(kt + 1, Ks[cur ^ 1]); STAGE_V(kt + 1, Vs[cur ^ 1]); }
        const unsigned long long mw = mrow[kt];
        const uint32_t mlo = (uint32_t)mw >> (g * 8);
        const uint32_t mhi = (uint32_t)(mw >> 32) >> (g * 8);

        const char* Kb = Ks[cur] + lane * 16;
        short8 bk[4][2];
        #pragma unroll
        for (int t = 0; t < 4; ++t)
            #pragma unroll
            for (int h = 0; h < 2; ++h)
                bk[t][h] = *(const short8*)(Kb + (t * 2 + h) * 1024);

        float4v accs[4];
        #pragma unroll
        for (int t = 0; t < 4; ++t) accs[t] = (float4v){0.f, 0.f, 0.f, 0.f};
        #pragma unroll
        for (int t = 0; t < 4; ++t) {
            accs[t] = __builtin_amdgcn_mfma_f32_16x16x32_bf16(bk[t][0], aq[0], accs[t], 0, 0, 0);
            accs[t] = __builtin_amdgcn_mfma_f32_16x16x32_bf16(bk[t][1], aq[1], accs[t], 0, 0, 0);
        }

        // normalized P, fully in registers: p = mask ? exp2(acc + log2(1/l)) : 0
        const uint32_t nib[4] = { mlo & 0xFu, (mlo >> 4) & 0xFu, mhi & 0xFu, (mhi >> 4) & 0xFu };
        float4v pv[4];
        #pragma unroll
        for (int t = 0; t < 4; ++t) {
            #pragma unroll
            for (int r = 0; r < 4; ++r) {
                const float e = exp2_hw(accs[t][r] + linv2);
                pv[t][r] = ((nib[t] >> r) & 1u) ? e : 0.f;
            }
        }

        // attn store: lane (g,li) owns kv = {8g..8g+7, 32+8g..32+8g+7} of its q-row
        float* ap = attnT + kt * KT;
        *(float4v*)(ap)      = pv[0];
        *(float4v*)(ap + 4)  = pv[1];
        *(float4v*)(ap + 32) = pv[2];
        *(float4v*)(ap + 36) = pv[3];

        // PV B-fragment = register rename of packed pv
        uint32_t pk[4][2];
        #pragma unroll
        for (int t = 0; t < 4; ++t) {
            pk[t][0] = cvt_pk_bf16(pv[t][0], pv[t][1]);
            pk[t][1] = cvt_pk_bf16(pv[t][2], pv[t][3]);
        }
        union { uint32_t u[4]; short8 s; } pa0, pa1;
        pa0.u[0] = pk[0][0]; pa0.u[1] = pk[0][1]; pa0.u[2] = pk[1][0]; pa0.u[3] = pk[1][1];
        pa1.u[0] = pk[2][0]; pa1.u[1] = pk[2][1]; pa1.u[2] = pk[3][0]; pa1.u[3] = pk[3][1];

        const char* Vb = Vs[cur] + lane * 16;
        #pragma unroll
        for (int dt = 0; dt < 4; ++dt) {
            short8 vb0 = *(const short8*)(Vb + (dt * 2 + 0) * 1024);
            short8 vb1 = *(const short8*)(Vb + (dt * 2 + 1) * 1024);
            acco[dt] = __builtin_amdgcn_mfma_f32_16x16x32_bf16(vb0, pa0.s, acco[dt], 0, 0, 0);
            acco[dt] = __builtin_amdgcn_mfma_f32_16x16x32_bf16(vb1, pa1.s, acco[dt], 0, 0, 0);
        }
        __syncthreads();
        cur ^= 1;
    }

    // ---- write output: lane (g,li) owns out[qrow][dt*16+g*4 .. +3] ----
    float* outW = outg + qkvBase + (size_t)qrow * HD + g * 4;
    #pragma unroll
    for (int dt = 0; dt < 4; ++dt) {
        *(float4v*)(outW + dt * 16) = acco[dt];
    }
}

extern "C" void kernel_launch(void* const* d_in, const int* in_sizes, int n_in,
                              void* d_out, int out_size, void* d_ws, size_t ws_size,
                              hipStream_t stream) {
    (void)in_sizes; (void)n_in; (void)out_size; (void)ws_size;
    const float* q = (const float*)d_in[0];
    const float* k = (const float*)d_in[1];
    const float* v = (const float*)d_in[2];
    const int* mask = (const int*)d_in[3];

    float* outp  = (float*)d_out;
    float* attnp = outp + (size_t)2 * 8 * SEQ * HD;

    // ws layout: [0,2MB) mask bits | [2MB,10MB) K tiles | [10MB,18MB) V tiles
    char* ws = (char*)d_ws;
    unsigned long long* mb = (unsigned long long*)ws;
    char* ktiles = ws + (size_t)2 * 1024 * 1024;
    char* vtiles = ws + (size_t)10 * 1024 * 1024;

    pack_mask_kernel<<<SEQ, 256, 0, stream>>>(mask, mb);
    prep_kv_kernel<<<HEADS * (SEQ / KT), 256, 0, stream>>>(k, v, ktiles, vtiles);
    attn_kernel<<<HEADS * (SEQ / QB), 256, 0, stream>>>(q, mb, ktiles, vtiles, outp, attnp);
}